// Round 18
// baseline (43.936 us; speedup 1.0000x reference)
//
#include <hip/hip_runtime.h>
#include <hip/hip_bf16.h>

// out[m,u] = sum_t x[m,t] * W_eff[u,t] + b_eff[u]      (m = 32*512 rows)
//   W_eff = Ws + (Wt - Ws) @ A   (A = causal window-mean, window 25)
// Round-18: r17 verbatim (row-resident fold ~0.3us + r11 GEMM 41.7us) with
// ONE change: x loads and out stores are NON-TEMPORAL. x is read once per
// block and out never re-read; nt keeps the streaming 11.8 MB/XCD from
// evicting the shared 1.13 MB W image out of each XCD's 4 MB L2 (W-feed is
// the fitted bottleneck at ~54 B/cy/CU; thrash turns L2 hits into L3 misses).

#define Tdim  720
#define KP    736      // padded K (23*32); Wb zero-filled for k>=720
#define WROWS 768      // padded u-rows of Wb (zero rows >=720)
#define NK    23
#define BM    64       // m-rows per block
#define APAD  744      // LDS row stride in elems

using bf16x8 = __attribute__((ext_vector_type(8))) __bf16;
using f32x4  = __attribute__((ext_vector_type(4))) float;

__global__ __launch_bounds__(256)
void fold_w_kernel(const float* __restrict__ tw,
                   const float* __restrict__ tb,
                   const float* __restrict__ sw,
                   const float* __restrict__ sb,
                   __bf16* __restrict__ Wb,
                   float* __restrict__ beff) {
  __shared__ float D[744];            // tw-sw, zero-padded to i+24 max reach
  __shared__ float S[720];            // sw row

  const int u   = blockIdx.x;         // 0..767
  const int tid = threadIdx.x;

  if (u >= Tdim) {                    // pad rows of Wb: pure zeros
    for (int i = tid; i < KP; i += 256)
      Wb[(size_t)u * KP + i] = (__bf16)0.0f;
    return;
  }

  const float* twr = tw + (size_t)u * Tdim;
  const float* swr = sw + (size_t)u * Tdim;

  for (int j = tid; j < 180; j += 256) {      // 180 f32x4 units = 720 elems
    f32x4 a = ((const f32x4*)twr)[j];
    f32x4 b = ((const f32x4*)swr)[j];
    #pragma unroll
    for (int q = 0; q < 4; ++q) {
      D[j * 4 + q] = a[q] - b[q];
      S[j * 4 + q] = b[q];
    }
  }
  if (tid < 24) D[720 + tid] = 0.0f;          // window over-reach pad
  __syncthreads();

  for (int i = tid; i < KP; i += 256) {
    float w;
    if (i >= Tdim) {
      w = 0.0f;                                // K-pad cols of Wb
    } else {
      float acc = 0.0f;
      if (i >= 24) {
        #pragma unroll
        for (int t = 0; t < 25; ++t) acc += D[i + t];   // D pad makes tail exact
        acc *= 0.04f;
      } else {
        for (int t = i; t < i + 25; ++t) {
          float c = (t >= 24) ? 0.04f : 1.0f / (float)(t + 1);
          acc += D[t] * c;
        }
      }
      w = S[i] + acc;
    }
    Wb[(size_t)u * KP + i] = (__bf16)w;
  }
  if (tid == 0) beff[u] = tb[u] + sb[u];
}

__global__ __launch_bounds__(1024, 1)
void dlinear_gemm(const float* __restrict__ x,
                  const __bf16* __restrict__ Wb,
                  const float* __restrict__ beff,
                  float* __restrict__ out) {
  __shared__ __bf16 As[BM * APAD];   // 95232 B -> 1 block/CU

  const int tid  = threadIdx.x;
  const int lane = tid & 63;
  const int wid  = tid >> 6;          // 0..15
  const int lg = lane >> 4, lr = lane & 15;

  const int m0 = blockIdx.x * BM;
  const int u0 = wid * 48;            // wave owns 48 u-cols (768 = 16*48 padded)

  // ---- prologue: x[m0..m0+64) x [0..720) -> LDS bf16 (non-temporal reads)
  #pragma unroll
  for (int c = 0; c < 6; ++c) {
    int idx = tid + 1024 * c;         // 8-f32 chunk id; 90 chunks per row
    if (idx < BM * 90) {
      int row  = idx / 90;
      int col8 = idx - row * 90;
      const f32x4* p = (const f32x4*)(x + (size_t)(m0 + row) * Tdim + col8 * 8);
      f32x4 a0 = __builtin_nontemporal_load(p);
      f32x4 a1 = __builtin_nontemporal_load(p + 1);
      bf16x8 v;
      #pragma unroll
      for (int j = 0; j < 4; ++j) { v[j] = (__bf16)a0[j]; v[j + 4] = (__bf16)a1[j]; }
      *(bf16x8*)(&As[row * APAD + col8 * 8]) = v;
    }
  }
  {  // zero the K-pad [720,736): 64 rows x 16 elems = 1024 threads exactly
    int r = tid >> 4;
    int c = 720 + (tid & 15);
    As[r * APAD + c] = (__bf16)0.0f;
  }
  __syncthreads();                    // the ONLY barrier

  // ---- W stream pointers: frag ni -> row u0+ni*16+lr, 16B chunk lg within K-step
  const __bf16* wp[3];
  #pragma unroll
  for (int ni = 0; ni < 3; ++ni)
    wp[ni] = Wb + (size_t)(u0 + ni * 16 + lr) * KP + lg * 8;

  int arofs[4];
  #pragma unroll
  for (int mi = 0; mi < 4; ++mi) arofs[mi] = (mi * 16 + lr) * APAD + lg * 8;

  f32x4 acc[4][3];
  #pragma unroll
  for (int mi = 0; mi < 4; ++mi)
    #pragma unroll
    for (int ni = 0; ni < 3; ++ni) {
      f32x4 z; z[0] = 0.f; z[1] = 0.f; z[2] = 0.f; z[3] = 0.f;
      acc[mi][ni] = z;
    }

  // ---- K-loop: depth-2 W pipeline, 3 named slots, zero barriers.
  bf16x8 s0[3], s1[3], s2[3];
  #pragma unroll
  for (int ni = 0; ni < 3; ++ni) s0[ni] = *(const bf16x8*)(wp[ni]);        // W0
  #pragma unroll
  for (int ni = 0; ni < 3; ++ni) s1[ni] = *(const bf16x8*)(wp[ni] + 32);   // W1

#define GEMM_STEP(T, SLOT, ISSUE_SLOT, DO_ISSUE)                               \
  {                                                                            \
    if (DO_ISSUE) {                                                            \
      _Pragma("unroll")                                                        \
      for (int ni = 0; ni < 3; ++ni)                                           \
        ISSUE_SLOT[ni] = *(const bf16x8*)(wp[ni] + ((T) + 2) * 32);            \
    }                                                                          \
    bf16x8 av[4];                                                              \
    _Pragma("unroll")                                                          \
    for (int mi = 0; mi < 4; ++mi)                                             \
      av[mi] = *(const bf16x8*)(&As[arofs[mi] + (T) * 32]);                    \
    _Pragma("unroll")                                                          \
    for (int mi = 0; mi < 4; ++mi)                                             \
      _Pragma("unroll")                                                        \
      for (int ni = 0; ni < 3; ++ni)                                           \
        acc[mi][ni] = __builtin_amdgcn_mfma_f32_16x16x32_bf16(av[mi],          \
                        SLOT[ni], acc[mi][ni], 0, 0, 0);                       \
  }

  for (int t = 0; t < 21; t += 3) {    // t = 0,3,...,18 (covers 0..20)
    GEMM_STEP(t,     s0, s2, true)     // compute W(t),   issue W(t+2) -> s2
    GEMM_STEP(t + 1, s1, s0, true)     // compute W(t+1), issue W(t+3) -> s0
    GEMM_STEP(t + 2, s2, s1, true)     // compute W(t+2), issue W(t+4) -> s1
  }
  GEMM_STEP(21, s0, s2, false)         // W21 (loaded at t=18 phase b)
  GEMM_STEP(22, s1, s2, false)         // W22 (loaded at t=18 phase c)
#undef GEMM_STEP

  // ---- epilogue: non-temporal stores (out never re-read; keep W in L2)
  #pragma unroll
  for (int ni = 0; ni < 3; ++ni) {
    const int u = u0 + ni * 16 + lr;
    if (u >= Tdim) continue;
    const float bias = beff[u];
    #pragma unroll
    for (int mi = 0; mi < 4; ++mi) {
      const int mb = m0 + mi * 16 + lg * 4;
      #pragma unroll
      for (int j = 0; j < 4; ++j)
        __builtin_nontemporal_store(acc[mi][ni][j] + bias,
                                    &out[(size_t)(mb + j) * Tdim + u]);
    }
  }
}

extern "C" void kernel_launch(void* const* d_in, const int* in_sizes, int n_in,
                              void* d_out, int out_size, void* d_ws, size_t ws_size,
                              hipStream_t stream) {
  const float* x  = (const float*)d_in[0];
  const float* tw = (const float*)d_in[1];
  const float* tb = (const float*)d_in[2];
  const float* sw = (const float*)d_in[3];
  const float* sb = (const float*)d_in[4];
  float* out = (float*)d_out;

  __bf16* Wb  = (__bf16*)d_ws;
  float* beff = (float*)((char*)d_ws + (size_t)WROWS * KP * sizeof(__bf16));

  fold_w_kernel<<<dim3(WROWS), dim3(256), 0, stream>>>(tw, tb, sw, sb, Wb, beff);

  const int M = in_sizes[0] / Tdim;            // 16384
  dim3 grid(M / BM);                           // 256 blocks, 1 per CU
  dlinear_gemm<<<grid, dim3(1024), 0, stream>>>(x, Wb, beff, out);
}

// Round 19
// 41.395 us; speedup vs baseline: 1.0614x; 1.0614x over previous
//
#include <hip/hip_runtime.h>
#include <hip/hip_bf16.h>

// out[m,u] = sum_t x[m,t] * W_eff[u,t] + b_eff[u]      (m = 32*512 rows)
//   W_eff = Ws + (Wt - Ws) @ A   (A = causal window-mean, window 25)
// Round-19: r17 verbatim (row-resident fold + r11 GEMM, best total 42.0us)
// + T5 s_setprio(1) around each MFMA cluster. Regime check: the K-loop has
// ZERO barriers -> 16 waves/CU drift across {W-load / LDS-read / MFMA}
// roles (m191-style independent-wave regime, where setprio is +4-7%), not
// the m190 barrier-lockstep regime (where it was null/-1.5%).

#define Tdim  720
#define KP    736      // padded K (23*32); Wb zero-filled for k>=720
#define WROWS 768      // padded u-rows of Wb (zero rows >=720)
#define NK    23
#define BM    64       // m-rows per block
#define APAD  744      // LDS row stride in elems

using bf16x8 = __attribute__((ext_vector_type(8))) __bf16;
using f32x4  = __attribute__((ext_vector_type(4))) float;

__global__ __launch_bounds__(256)
void fold_w_kernel(const float* __restrict__ tw,
                   const float* __restrict__ tb,
                   const float* __restrict__ sw,
                   const float* __restrict__ sb,
                   __bf16* __restrict__ Wb,
                   float* __restrict__ beff) {
  __shared__ float D[744];            // tw-sw, zero-padded to i+24 max reach
  __shared__ float S[720];            // sw row

  const int u   = blockIdx.x;         // 0..767
  const int tid = threadIdx.x;

  if (u >= Tdim) {                    // pad rows of Wb: pure zeros
    for (int i = tid; i < KP; i += 256)
      Wb[(size_t)u * KP + i] = (__bf16)0.0f;
    return;
  }

  const float* twr = tw + (size_t)u * Tdim;
  const float* swr = sw + (size_t)u * Tdim;

  for (int j = tid; j < 180; j += 256) {      // 180 f32x4 units = 720 elems
    f32x4 a = ((const f32x4*)twr)[j];
    f32x4 b = ((const f32x4*)swr)[j];
    #pragma unroll
    for (int q = 0; q < 4; ++q) {
      D[j * 4 + q] = a[q] - b[q];
      S[j * 4 + q] = b[q];
    }
  }
  if (tid < 24) D[720 + tid] = 0.0f;          // window over-reach pad
  __syncthreads();

  for (int i = tid; i < KP; i += 256) {
    float w;
    if (i >= Tdim) {
      w = 0.0f;                                // K-pad cols of Wb
    } else {
      float acc = 0.0f;
      if (i >= 24) {
        #pragma unroll
        for (int t = 0; t < 25; ++t) acc += D[i + t];   // D pad makes tail exact
        acc *= 0.04f;
      } else {
        for (int t = i; t < i + 25; ++t) {
          float c = (t >= 24) ? 0.04f : 1.0f / (float)(t + 1);
          acc += D[t] * c;
        }
      }
      w = S[i] + acc;
    }
    Wb[(size_t)u * KP + i] = (__bf16)w;
  }
  if (tid == 0) beff[u] = tb[u] + sb[u];
}

__global__ __launch_bounds__(1024, 1)
void dlinear_gemm(const float* __restrict__ x,
                  const __bf16* __restrict__ Wb,
                  const float* __restrict__ beff,
                  float* __restrict__ out) {
  __shared__ __bf16 As[BM * APAD];   // 95232 B -> 1 block/CU

  const int tid  = threadIdx.x;
  const int lane = tid & 63;
  const int wid  = tid >> 6;          // 0..15
  const int lg = lane >> 4, lr = lane & 15;

  const int m0 = blockIdx.x * BM;
  const int u0 = wid * 48;            // wave owns 48 u-cols (768 = 16*48 padded)

  // ---- prologue: x[m0..m0+64) x [0..720) -> LDS bf16 (coalesced 32B/lane)
  #pragma unroll
  for (int c = 0; c < 6; ++c) {
    int idx = tid + 1024 * c;         // 8-f32 chunk id; 90 chunks per row
    if (idx < BM * 90) {
      int row  = idx / 90;
      int col8 = idx - row * 90;
      const float* p = x + (size_t)(m0 + row) * Tdim + col8 * 8;
      f32x4 a0 = ((const f32x4*)p)[0];
      f32x4 a1 = ((const f32x4*)p)[1];
      bf16x8 v;
      #pragma unroll
      for (int j = 0; j < 4; ++j) { v[j] = (__bf16)a0[j]; v[j + 4] = (__bf16)a1[j]; }
      *(bf16x8*)(&As[row * APAD + col8 * 8]) = v;
    }
  }
  {  // zero the K-pad [720,736): 64 rows x 16 elems = 1024 threads exactly
    int r = tid >> 4;
    int c = 720 + (tid & 15);
    As[r * APAD + c] = (__bf16)0.0f;
  }
  __syncthreads();                    // the ONLY barrier

  // ---- W stream pointers: frag ni -> row u0+ni*16+lr, 16B chunk lg within K-step
  const __bf16* wp[3];
  #pragma unroll
  for (int ni = 0; ni < 3; ++ni)
    wp[ni] = Wb + (size_t)(u0 + ni * 16 + lr) * KP + lg * 8;

  int arofs[4];
  #pragma unroll
  for (int mi = 0; mi < 4; ++mi) arofs[mi] = (mi * 16 + lr) * APAD + lg * 8;

  f32x4 acc[4][3];
  #pragma unroll
  for (int mi = 0; mi < 4; ++mi)
    #pragma unroll
    for (int ni = 0; ni < 3; ++ni) {
      f32x4 z; z[0] = 0.f; z[1] = 0.f; z[2] = 0.f; z[3] = 0.f;
      acc[mi][ni] = z;
    }

  // ---- K-loop: depth-2 W pipeline, 3 named slots, zero barriers.
  bf16x8 s0[3], s1[3], s2[3];
  #pragma unroll
  for (int ni = 0; ni < 3; ++ni) s0[ni] = *(const bf16x8*)(wp[ni]);        // W0
  #pragma unroll
  for (int ni = 0; ni < 3; ++ni) s1[ni] = *(const bf16x8*)(wp[ni] + 32);   // W1

#define GEMM_STEP(T, SLOT, ISSUE_SLOT, DO_ISSUE)                               \
  {                                                                            \
    if (DO_ISSUE) {                                                            \
      _Pragma("unroll")                                                        \
      for (int ni = 0; ni < 3; ++ni)                                           \
        ISSUE_SLOT[ni] = *(const bf16x8*)(wp[ni] + ((T) + 2) * 32);            \
    }                                                                          \
    bf16x8 av[4];                                                              \
    _Pragma("unroll")                                                          \
    for (int mi = 0; mi < 4; ++mi)                                             \
      av[mi] = *(const bf16x8*)(&As[arofs[mi] + (T) * 32]);                    \
    __builtin_amdgcn_s_setprio(1);                                             \
    _Pragma("unroll")                                                          \
    for (int mi = 0; mi < 4; ++mi)                                             \
      _Pragma("unroll")                                                        \
      for (int ni = 0; ni < 3; ++ni)                                           \
        acc[mi][ni] = __builtin_amdgcn_mfma_f32_16x16x32_bf16(av[mi],          \
                        SLOT[ni], acc[mi][ni], 0, 0, 0);                       \
    __builtin_amdgcn_s_setprio(0);                                             \
  }

  for (int t = 0; t < 21; t += 3) {    // t = 0,3,...,18 (covers 0..20)
    GEMM_STEP(t,     s0, s2, true)     // compute W(t),   issue W(t+2) -> s2
    GEMM_STEP(t + 1, s1, s0, true)     // compute W(t+1), issue W(t+3) -> s0
    GEMM_STEP(t + 2, s2, s1, true)     // compute W(t+2), issue W(t+4) -> s1
  }
  GEMM_STEP(21, s0, s2, false)         // W21 (loaded at t=18 phase b)
  GEMM_STEP(22, s1, s2, false)         // W22 (loaded at t=18 phase c)
#undef GEMM_STEP

  // ---- epilogue: C/D layout col = lr -> u, row = lg*4 + j -> m
  #pragma unroll
  for (int ni = 0; ni < 3; ++ni) {
    const int u = u0 + ni * 16 + lr;
    if (u >= Tdim) continue;
    const float bias = beff[u];
    #pragma unroll
    for (int mi = 0; mi < 4; ++mi) {
      const int mb = m0 + mi * 16 + lg * 4;
      #pragma unroll
      for (int j = 0; j < 4; ++j)
        out[(size_t)(mb + j) * Tdim + u] = acc[mi][ni][j] + bias;
    }
  }
}

extern "C" void kernel_launch(void* const* d_in, const int* in_sizes, int n_in,
                              void* d_out, int out_size, void* d_ws, size_t ws_size,
                              hipStream_t stream) {
  const float* x  = (const float*)d_in[0];
  const float* tw = (const float*)d_in[1];
  const float* tb = (const float*)d_in[2];
  const float* sw = (const float*)d_in[3];
  const float* sb = (const float*)d_in[4];
  float* out = (float*)d_out;

  __bf16* Wb  = (__bf16*)d_ws;
  float* beff = (float*)((char*)d_ws + (size_t)WROWS * KP * sizeof(__bf16));

  fold_w_kernel<<<dim3(WROWS), dim3(256), 0, stream>>>(tw, tb, sw, sb, Wb, beff);

  const int M = in_sizes[0] / Tdim;            // 16384
  dim3 grid(M / BM);                           // 256 blocks, 1 per CU
  dlinear_gemm<<<grid, dim3(1024), 0, stream>>>(x, Wb, beff, out);
}